// Round 4
// baseline (1066.096 us; speedup 1.0000x reference)
//
#include <hip/hip_runtime.h>
#include <hip/hip_bf16.h>

// CONCATNet forward. B=512 NW=256 NS=8 P=32 D=512 H=16 QK=32 A=34
// R4: KS/VS/SS merged into one N=1536 MFMA GEMM (shared A staging, 1632
// blocks); assembleE fused into E-GEMM epilogue; ctx 3-GEMMs fused into one
// z-indexed kernel. Split-bf16 (hi*hi + hi*lo + lo*hi) for fp32-grade MFMA.
// action_mask arrives as int32 (harness widens bool).

#define B_  512
#define NW_ 256
#define NS_ 8
#define P_  32
#define D_  512
#define H_  16
#define QK_ 32
#define A_  34

typedef __attribute__((ext_vector_type(8))) short short8;
typedef __attribute__((ext_vector_type(4))) float floatx4;

// ---------------------------------------------------------------- bf16 split
__device__ __forceinline__ unsigned short bf16_rne(float x) {
    union { float f; unsigned int u; } c; c.f = x;
    unsigned int u = c.u;
    return (unsigned short)((u + 0x7fffu + ((u >> 16) & 1u)) >> 16);
}
__device__ __forceinline__ float bf16_f(unsigned short h) {
    union { unsigned int u; float f; } c; c.u = ((unsigned int)h) << 16;
    return c.f;
}
__device__ __forceinline__ void bf16_split(float x, unsigned short& hi, unsigned short& lo) {
    hi = bf16_rne(x);
    lo = bf16_rne(x - bf16_f(hi));
}

__device__ __forceinline__ void gload16(const void* g, void* l) {
    __builtin_amdgcn_global_load_lds(
        (const __attribute__((address_space(1))) void*)g,
        (__attribute__((address_space(3))) void*)l, 16, 0, 0);
}

// ---------------------------------------------------------------- MFMA GEMM
// C[M,ldc slice] = sum over passes of Abf[m, aoff+k] * Wbf[n, woff+k]
// Abf: [M,1024] bf16 hi|lo packed. Wbf: [Nrows,1024] same.
// Epilogues: plain (+rank-1), or fused-E (colemb gather + rank1 + re-split).
struct Pass { const unsigned short* a; const unsigned short* w; int aoff; int woff; };
struct GemmCfg {
    Pass p[6];
    int npass;
    float* C;
    int ldc;
    const float* r1row;
    const float* r1col;
    int fuseE;
    const float* colemb;
    const float* c_pm;
    const float* remain;
    const int* idxs;
    unsigned short* Epack;
};

__global__ __launch_bounds__(256) void gemm_mfma(GemmCfg cfg)
{
    __shared__ __align__(16) unsigned short As[128 * 32];
    __shared__ __align__(16) unsigned short Ws[128 * 32];

    const int tid  = threadIdx.x;
    const int m0   = blockIdx.y * 128;
    const int n0   = blockIdx.x * 128;
    const int wave = tid >> 6;
    const int lane = tid & 63;
    const int wr   = wave >> 1;
    const int wc   = wave & 1;
    const int lrow = tid >> 2;
    const int lpart= (tid & 3) << 3;

    floatx4 acc[4][4];
#pragma unroll
    for (int i = 0; i < 4; i++)
#pragma unroll
        for (int j = 0; j < 4; j++) acc[i][j] = (floatx4)0.f;

    const int q = lane >> 4;
    const int r = lane & 15;

    for (int pi = 0; pi < cfg.npass; ++pi) {
        const unsigned short* Ab = cfg.p[pi].a + (size_t)m0 * 1024 + cfg.p[pi].aoff;
        const unsigned short* Wb = cfg.p[pi].w + (size_t)n0 * 1024 + cfg.p[pi].woff;
        for (int k0 = 0; k0 < 512; k0 += 32) {
            __syncthreads();
            gload16(Ab + (size_t)lrow * 1024 + k0 + lpart,        &As[tid * 8]);
            gload16(Ab + (size_t)(lrow + 64) * 1024 + k0 + lpart, &As[2048 + tid * 8]);
            gload16(Wb + (size_t)lrow * 1024 + k0 + lpart,        &Ws[tid * 8]);
            gload16(Wb + (size_t)(lrow + 64) * 1024 + k0 + lpart, &Ws[2048 + tid * 8]);
            __syncthreads();

            short8 af[4], wf[4];
#pragma unroll
            for (int i = 0; i < 4; i++)
                af[i] = *(const short8*)&As[(wr * 64 + i * 16 + r) * 32 + q * 8];
#pragma unroll
            for (int j = 0; j < 4; j++)
                wf[j] = *(const short8*)&Ws[(wc * 64 + j * 16 + r) * 32 + q * 8];
#pragma unroll
            for (int i = 0; i < 4; i++)
#pragma unroll
                for (int j = 0; j < 4; j++)
                    acc[i][j] = __builtin_amdgcn_mfma_f32_16x16x32_bf16(
                        af[i], wf[j], acc[i][j], 0, 0, 0);
        }
    }

    if (cfg.fuseE) {
        // E = acc + colemb[stage] + remain*c_pm (rows a>=2), 0 for a<2.
        // Writes fp32 E (C) and bf16 hi|lo Epack.
#pragma unroll
        for (int j = 0; j < 4; j++) {
            const int col = n0 + wc * 64 + j * 16 + r;
            const float cpm = cfg.c_pm[col];
#pragma unroll
            for (int i = 0; i < 4; i++) {
                const int rowb = m0 + wr * 64 + i * 16 + q * 4;
#pragma unroll
                for (int reg = 0; reg < 4; reg++) {
                    const int m = rowb + reg;
                    const int b = m / A_;
                    const int a = m - b * A_;
                    float v = 0.f;
                    if (a >= 2) {
                        const int p = a - 2;
                        const int s = cfg.idxs[b * P_ + p];
                        v = acc[i][j][reg]
                          + cfg.colemb[((size_t)(b * NS_ + s)) * 512 + col]
                          + cfg.remain[b * P_ + p] * cpm;
                    }
                    cfg.C[(size_t)m * 512 + col] = v;
                    unsigned short hh, ll;
                    bf16_split(v, hh, ll);
                    cfg.Epack[(size_t)m * 1024 + col] = hh;
                    cfg.Epack[(size_t)m * 1024 + 512 + col] = ll;
                }
            }
        }
    } else {
#pragma unroll
        for (int j = 0; j < 4; j++) {
            const int col = n0 + wc * 64 + j * 16 + r;
            const float r1c = cfg.r1col ? cfg.r1col[col] : 0.f;
#pragma unroll
            for (int i = 0; i < 4; i++) {
                const int rowb = m0 + wr * 64 + i * 16 + q * 4;
#pragma unroll
                for (int reg = 0; reg < 4; reg++) {
                    float v = acc[i][j][reg];
                    if (cfg.r1row) v += cfg.r1row[rowb + reg] * r1c;
                    cfg.C[(size_t)(rowb + reg) * cfg.ldc + col] = v;
                }
            }
        }
    }
}

// ---------------------------------------------------------------- fp32 GEMM (small)
#define BM 64
#define BN 64
#define BK 32
__global__ __launch_bounds__(256) void gemm_nt(
    const float* __restrict__ A, int lda,
    const float* __restrict__ W, int ldw,
    float* __restrict__ C, int ldc,
    int K,
    const float* __restrict__ bias,
    int relu)
{
    __shared__ float As[BK][BM + 4];
    __shared__ float Wsm[BK][BN + 4];

    const int tid = threadIdx.x;
    const int m0 = blockIdx.y * BM;
    const int n0 = blockIdx.x * BN;
    const int ty = tid >> 4;
    const int tx = tid & 15;
    const int lrow = tid >> 2;
    const int lcol = (tid & 3) << 3;

    float acc[4][4];
#pragma unroll
    for (int i = 0; i < 4; i++)
#pragma unroll
        for (int j = 0; j < 4; j++) acc[i][j] = 0.f;

    const float* Ablk = A + (size_t)m0 * lda;
    const float* Wblk = W + (size_t)n0 * ldw;

    for (int k0 = 0; k0 < K; k0 += BK) {
        const float* ap = Ablk + (size_t)lrow * lda + k0 + lcol;
        float4 a0 = *(const float4*)(ap);
        float4 a1 = *(const float4*)(ap + 4);
        const float* wp = Wblk + (size_t)lrow * ldw + k0 + lcol;
        float4 w0 = *(const float4*)(wp);
        float4 w1 = *(const float4*)(wp + 4);

        __syncthreads();
        As[lcol + 0][lrow] = a0.x; As[lcol + 1][lrow] = a0.y;
        As[lcol + 2][lrow] = a0.z; As[lcol + 3][lrow] = a0.w;
        As[lcol + 4][lrow] = a1.x; As[lcol + 5][lrow] = a1.y;
        As[lcol + 6][lrow] = a1.z; As[lcol + 7][lrow] = a1.w;
        Wsm[lcol + 0][lrow] = w0.x; Wsm[lcol + 1][lrow] = w0.y;
        Wsm[lcol + 2][lrow] = w0.z; Wsm[lcol + 3][lrow] = w0.w;
        Wsm[lcol + 4][lrow] = w1.x; Wsm[lcol + 5][lrow] = w1.y;
        Wsm[lcol + 6][lrow] = w1.z; Wsm[lcol + 7][lrow] = w1.w;
        __syncthreads();

#pragma unroll
        for (int k = 0; k < BK; k++) {
            const float4 av = *(const float4*)(&As[k][ty << 2]);
            const float4 wv = *(const float4*)(&Wsm[k][tx << 2]);
            acc[0][0] += av.x * wv.x; acc[0][1] += av.x * wv.y;
            acc[0][2] += av.x * wv.z; acc[0][3] += av.x * wv.w;
            acc[1][0] += av.y * wv.x; acc[1][1] += av.y * wv.y;
            acc[1][2] += av.y * wv.z; acc[1][3] += av.y * wv.w;
            acc[2][0] += av.z * wv.x; acc[2][1] += av.z * wv.y;
            acc[2][2] += av.z * wv.z; acc[2][3] += av.z * wv.w;
            acc[3][0] += av.w * wv.x; acc[3][1] += av.w * wv.y;
            acc[3][2] += av.w * wv.z; acc[3][3] += av.w * wv.w;
        }
    }

    const int mbase = m0 + (ty << 2);
    const int nbase = n0 + (tx << 2);
    float4 bv = make_float4(0.f, 0.f, 0.f, 0.f);
    if (bias) bv = *(const float4*)(bias + nbase);

#pragma unroll
    for (int i = 0; i < 4; i++) {
        float* cp = C + (size_t)(mbase + i) * ldc + nbase;
        float4 v = make_float4(acc[i][0], acc[i][1], acc[i][2], acc[i][3]);
        if (bias) { v.x += bv.x; v.y += bv.y; v.z += bv.z; v.w += bv.w; }
        if (relu) {
            v.x = fmaxf(v.x, 0.f); v.y = fmaxf(v.y, 0.f);
            v.z = fmaxf(v.z, 0.f); v.w = fmaxf(v.w, 0.f);
        }
        *(float4*)cp = v;
    }
}

// ---------------------------------------------------------------- ctx 3-in-1
// z=0: ctx[:,0:1024 slice? no -> writes ctx+z*512] ; A/W/K per z.
struct Ctx3Cfg {
    const float* A0; const float* A1; const float* A2;
    const float* W0; const float* W1; const float* W2;
    float* C;
};
__global__ __launch_bounds__(256) void ctx3_kernel(Ctx3Cfg cfg)
{
    const int z = blockIdx.z;
    const float* A = (z == 0) ? cfg.A0 : (z == 1) ? cfg.A1 : cfg.A2;
    const float* W = (z == 0) ? cfg.W0 : (z == 1) ? cfg.W1 : cfg.W2;
    const int K = (z == 0) ? 1024 : 512;
    const int lda = K, ldw = K;
    float* C = cfg.C + z * 512;
    const int ldc = 1536;

    __shared__ float As[BK][BM + 4];
    __shared__ float Wsm[BK][BN + 4];

    const int tid = threadIdx.x;
    const int m0 = blockIdx.y * BM;
    const int n0 = blockIdx.x * BN;
    const int ty = tid >> 4;
    const int tx = tid & 15;
    const int lrow = tid >> 2;
    const int lcol = (tid & 3) << 3;

    float acc[4][4];
#pragma unroll
    for (int i = 0; i < 4; i++)
#pragma unroll
        for (int j = 0; j < 4; j++) acc[i][j] = 0.f;

    const float* Ablk = A + (size_t)m0 * lda;
    const float* Wblk = W + (size_t)n0 * ldw;

    for (int k0 = 0; k0 < K; k0 += BK) {
        const float* ap = Ablk + (size_t)lrow * lda + k0 + lcol;
        float4 a0 = *(const float4*)(ap);
        float4 a1 = *(const float4*)(ap + 4);
        const float* wp = Wblk + (size_t)lrow * ldw + k0 + lcol;
        float4 w0 = *(const float4*)(wp);
        float4 w1 = *(const float4*)(wp + 4);

        __syncthreads();
        As[lcol + 0][lrow] = a0.x; As[lcol + 1][lrow] = a0.y;
        As[lcol + 2][lrow] = a0.z; As[lcol + 3][lrow] = a0.w;
        As[lcol + 4][lrow] = a1.x; As[lcol + 5][lrow] = a1.y;
        As[lcol + 6][lrow] = a1.z; As[lcol + 7][lrow] = a1.w;
        Wsm[lcol + 0][lrow] = w0.x; Wsm[lcol + 1][lrow] = w0.y;
        Wsm[lcol + 2][lrow] = w0.z; Wsm[lcol + 3][lrow] = w0.w;
        Wsm[lcol + 4][lrow] = w1.x; Wsm[lcol + 5][lrow] = w1.y;
        Wsm[lcol + 6][lrow] = w1.z; Wsm[lcol + 7][lrow] = w1.w;
        __syncthreads();

#pragma unroll
        for (int k = 0; k < BK; k++) {
            const float4 av = *(const float4*)(&As[k][ty << 2]);
            const float4 wv = *(const float4*)(&Wsm[k][tx << 2]);
            acc[0][0] += av.x * wv.x; acc[0][1] += av.x * wv.y;
            acc[0][2] += av.x * wv.z; acc[0][3] += av.x * wv.w;
            acc[1][0] += av.y * wv.x; acc[1][1] += av.y * wv.y;
            acc[1][2] += av.y * wv.z; acc[1][3] += av.y * wv.w;
            acc[2][0] += av.z * wv.x; acc[2][1] += av.z * wv.y;
            acc[2][2] += av.z * wv.z; acc[2][3] += av.z * wv.w;
            acc[3][0] += av.w * wv.x; acc[3][1] += av.w * wv.y;
            acc[3][2] += av.w * wv.z; acc[3][3] += av.w * wv.w;
        }
    }

    const int mbase = m0 + (ty << 2);
    const int nbase = n0 + (tx << 2);
#pragma unroll
    for (int i = 0; i < 4; i++) {
        float* cp = C + (size_t)(mbase + i) * ldc + nbase;
        *(float4*)cp = make_float4(acc[i][0], acc[i][1], acc[i][2], acc[i][3]);
    }
}

// ---------------------------------------------------------------- prep scalars
__global__ __launch_bounds__(64) void prep_kernel(
    const float* __restrict__ clockp, const float* __restrict__ lpet,
    const int* __restrict__ loc_id, const int* __restrict__ robot_loc,
    const int* __restrict__ lhw, const int* __restrict__ lstage,
    float* __restrict__ dallA, float* __restrict__ remain,
    int* __restrict__ idxw, int* __restrict__ idxs)
{
    const int b = blockIdx.x;
    const int t = threadIdx.x;
    const float ck = clockp[b];
    const int rb = robot_loc[b];
    if (t < P_) {
        const float endt = lpet[b * P_ + t];
        const int lid = loc_id[b * P_ + t];
        const float pk = ck + 3.f * (lid != rb ? 1.f : 0.f);
        dallA[b * A_ + 2 + t] = (fmaxf(endt, pk) + 9.f - ck) * (1.f / 300.f);
        remain[b * P_ + t] = fmaxf(endt - ck, 0.f) * (1.f / 300.f);
        const int w = lhw[b * P_ + t];
        idxw[b * P_ + t] = (w >= 0) ? w : NW_;
        idxs[b * P_ + t] = lstage[b * P_ + t] - 1;
    } else if (t == P_) {
        const float d0 = (3.f * (rb != 0 ? 1.f : 0.f) + 9.f) * (1.f / 300.f);
        dallA[b * A_ + 0] = d0;
        dallA[b * A_ + 1] = d0;
    }
}

// ---------------------------------------------------------------- rank-1 vecs
// cvec[0:512]=c_pm  [512:1024]=c_k  [1024:1536]=c_v  [1536:2048]=c_shk
__global__ __launch_bounds__(256) void cvec_kernel(
    const float* __restrict__ W_dyn, const float* __restrict__ W_time,
    const float* __restrict__ W_pmcat, const float* __restrict__ Wk,
    const float* __restrict__ Wv, const float* __restrict__ Wshk,
    float* __restrict__ cvec)
{
    const int id = blockIdx.x * 256 + threadIdx.x;
    const int vec = id >> 9;
    const int h = id & 511;
    float s = 0.f;
    if (vec == 0) {
        const float* wp = W_pmcat + (size_t)h * 1536 + 1024;
        for (int j = 0; j < 512; j++) s += W_dyn[j * 2] * wp[j];
    } else {
        const float* Wm = (vec == 1) ? Wk : (vec == 2) ? Wv : Wshk;
        const float* wp = Wm + (size_t)h * 1536 + 1024;
        for (int j = 0; j < 512; j++) s += W_time[j] * wp[j];
    }
    cvec[id] = s;
}

// ---------------------------------------------------------------- pack weights
// Layout in Wpack (shorts):
//   Wp1   @ 0          [512,1024]   (pmcat cols 0..511)
//   Wp2   @ 524288     [512,1024]   (pmcat cols 512..1023)
//   Wkvs1 @ 1048576    [1536,1024]  (k|v|shk cols 0..511)
//   Wkvs2 @ 2621440    [1536,1024]  (k|v|shk cols 512..1023)
__global__ __launch_bounds__(128) void packW_kernel(
    const float* __restrict__ Wp, const float* __restrict__ Wk,
    const float* __restrict__ Wv, const float* __restrict__ Wsh,
    unsigned short* __restrict__ out)
{
    const int row = blockIdx.x;
    const int ms = blockIdx.y;          // 0..7
    const int mat = ms >> 1, seg = ms & 1;
    const int d = threadIdx.x * 4;
    const float* src = (mat == 0 ? Wp : mat == 1 ? Wk : mat == 2 ? Wv : Wsh)
                       + (size_t)row * 1536 + seg * 512 + d;
    const float4 v = *(const float4*)src;
    unsigned short h0, h1, h2, h3, l0, l1, l2, l3;
    bf16_split(v.x, h0, l0); bf16_split(v.y, h1, l1);
    bf16_split(v.z, h2, l2); bf16_split(v.w, h3, l3);
    unsigned short* dst;
    if (mat == 0) {
        dst = out + (size_t)seg * 524288 + (size_t)row * 1024 + d;
    } else {
        const int rr = (mat - 1) * 512 + row;
        dst = out + 1048576 + (size_t)seg * 1572864 + (size_t)rr * 1024 + d;
    }
    *(ushort4*)dst = make_ushort4(h0, h1, h2, h3);
    *(ushort4*)(dst + 512) = make_ushort4(l0, l1, l2, l3);
}

// ---------------------------------------------------------------- convert enc_col
__global__ __launch_bounds__(128) void packcol_kernel(
    const float* __restrict__ src, unsigned short* __restrict__ dst)
{
    const int row = blockIdx.x;
    const int d = threadIdx.x * 4;
    const float4 v = *(const float4*)(src + (size_t)row * 512 + d);
    unsigned short h0, h1, h2, h3, l0, l1, l2, l3;
    bf16_split(v.x, h0, l0); bf16_split(v.y, h1, l1);
    bf16_split(v.z, h2, l2); bf16_split(v.w, h3, l3);
    unsigned short* dp = dst + (size_t)row * 1024 + d;
    *(ushort4*)dp = make_ushort4(h0, h1, h2, h3);
    *(ushort4*)(dp + 512) = make_ushort4(l0, l1, l2, l3);
}

// ---------------------------------------------------------------- gather G
__global__ __launch_bounds__(128) void gatherG_kernel(
    const float* __restrict__ enc_row, const int* __restrict__ ll1,
    const int* __restrict__ ll2, const int* __restrict__ idxw,
    unsigned short* __restrict__ Gpack, float* __restrict__ Gll)
{
    const int ba = blockIdx.x;
    const int b = ba / A_, a = ba % A_;
    const int d = threadIdx.x * 4;
    int row;
    if (a == 0) row = ll1[b];
    else if (a == 1) row = ll2[b];
    else row = idxw[b * P_ + a - 2];
    float4 v = make_float4(0.f, 0.f, 0.f, 0.f);
    if (row < NW_) v = *(const float4*)(enc_row + ((size_t)b * NW_ + row) * D_ + d);
    unsigned short h0, h1, h2, h3, l0, l1, l2, l3;
    bf16_split(v.x, h0, l0); bf16_split(v.y, h1, l1);
    bf16_split(v.z, h2, l2); bf16_split(v.w, h3, l3);
    unsigned short* dp = Gpack + (size_t)ba * 1024 + d;
    *(ushort4*)dp = make_ushort4(h0, h1, h2, h3);
    *(ushort4*)(dp + 512) = make_ushort4(l0, l1, l2, l3);
    if (a < 2) *(float4*)(Gll + (size_t)b * 1024 + a * 512 + d) = v;
}

// ---------------------------------------------------------------- mean + rb gather
__global__ __launch_bounds__(128) void meanrb_kernel(
    const float* __restrict__ E, const int* __restrict__ robot_loc,
    float* __restrict__ Xpm, float* __restrict__ Xrb)
{
    const int b = blockIdx.x;
    const int d = threadIdx.x * 4;
    const float* ep = E + ((size_t)b * A_ + 2) * D_ + d;
    float4 acc = make_float4(0.f, 0.f, 0.f, 0.f);
    for (int p = 0; p < P_; p++) {
        const float4 v = *(const float4*)(ep + (size_t)p * D_);
        acc.x += v.x; acc.y += v.y; acc.z += v.z; acc.w += v.w;
    }
    const float inv = 1.f / (float)P_;
    acc.x *= inv; acc.y *= inv; acc.z *= inv; acc.w *= inv;
    *(float4*)(Xpm + (size_t)b * D_ + d) = acc;
    const int rb = robot_loc[b];
    *(float4*)(Xrb + (size_t)b * D_ + d) =
        *(const float4*)(E + ((size_t)b * A_ + 2 + rb) * D_ + d);
}

// ---------------------------------------------------------------- attention
// KVS layout: [b*A + a, 1536] with cols 0:512=K, 512:1024=V, 1024:1536=SHK.
__global__ __launch_bounds__(64) void attn_kernel(
    const float* __restrict__ Q, const float* __restrict__ KVS,
    const int* __restrict__ mask, float* __restrict__ OUT)
{
    const int h = blockIdx.x, b = blockIdx.y;
    const int lane = threadIdx.x;
    __shared__ float w[A_];
    float s;
    if (lane < A_) {
        const float* qp = Q + (size_t)b * D_ + h * QK_;
        const float* kp = KVS + ((size_t)b * A_ + lane) * 1536 + h * QK_;
        float acc = 0.f;
#pragma unroll
        for (int i = 0; i < QK_; i += 4) {
            const float4 qv = *(const float4*)(qp + i);
            const float4 kv = *(const float4*)(kp + i);
            acc += qv.x * kv.x + qv.y * kv.y + qv.z * kv.z + qv.w * kv.w;
        }
        s = acc * 0.17677669529663687f;
        if (!mask[b * A_ + lane]) s += -1e10f;
    } else {
        s = -1e30f;
    }
    float m = s;
    for (int o = 32; o; o >>= 1) m = fmaxf(m, __shfl_xor(m, o));
    float p = (lane < A_) ? expf(s - m) : 0.f;
    float sum = p;
    for (int o = 32; o; o >>= 1) sum += __shfl_xor(sum, o);
    if (lane < A_) w[lane] = p / sum;
    __syncthreads();
    if (lane < QK_) {
        const float* vp = KVS + (size_t)b * A_ * 1536 + 512 + h * QK_ + lane;
        float acc = 0.f;
#pragma unroll 2
        for (int a = 0; a < A_; a++) acc += w[a] * vp[(size_t)a * 1536];
        OUT[(size_t)b * D_ + h * QK_ + lane] = acc;
    }
}

// ---------------------------------------------------------------- final
__global__ __launch_bounds__(320) void final_kernel(
    const float* __restrict__ MH, const float* __restrict__ KVS,
    const int* __restrict__ mask, float* __restrict__ out)
{
    const int b = blockIdx.x;
    const int t = threadIdx.x;
    __shared__ float mh[D_];
    __shared__ float sc[A_];
    for (int i = t; i < D_; i += 320) mh[i] = MH[(size_t)b * D_ + i];
    __syncthreads();
    const int a = t >> 3;
    const int part = t & 7;
    float s = 0.f;
    if (a < A_) {
        const float* sp = KVS + ((size_t)b * A_ + a) * 1536 + 1024 + part * 64;
        const float* mp = mh + part * 64;
#pragma unroll
        for (int i = 0; i < 64; i += 4) {
            const float4 v = *(const float4*)(sp + i);
            s += mp[i] * v.x + mp[i + 1] * v.y + mp[i + 2] * v.z + mp[i + 3] * v.w;
        }
    }
    s += __shfl_down(s, 4, 8);
    s += __shfl_down(s, 2, 8);
    s += __shfl_down(s, 1, 8);
    if (a < A_ && part == 0) {
        float v = 10.f * tanhf(s * 0.044194173824159216f);
        if (!mask[b * A_ + a]) v += -1e10f;
        sc[a] = v;
    }
    __syncthreads();
    if (t < 64) {
        float x = (t < A_) ? sc[t] : -1e30f;
        float m = x;
        for (int o = 32; o; o >>= 1) m = fmaxf(m, __shfl_xor(m, o));
        float p = (t < A_) ? expf(x - m) : 0.f;
        float sum = p;
        for (int o = 32; o; o >>= 1) sum += __shfl_xor(sum, o);
        if (t < A_) out[(size_t)b * A_ + t] = p / sum;
    }
}

// ---------------------------------------------------------------- launcher
extern "C" void kernel_launch(void* const* d_in, const int* in_sizes, int n_in,
                              void* d_out, int out_size, void* d_ws, size_t ws_size,
                              hipStream_t stream)
{
    const float* enc_row = (const float*)d_in[0];
    const float* enc_col = (const float*)d_in[1];
    const float* clockp  = (const float*)d_in[2];
    const float* lpet    = (const float*)d_in[3];
    const int* loc_id    = (const int*)d_in[4];
    const int* robot_loc = (const int*)d_in[5];
    const int* lhw       = (const int*)d_in[6];
    const int* lstage    = (const int*)d_in[7];
    const int* ll1       = (const int*)d_in[8];
    const int* ll2       = (const int*)d_in[9];
    const int* amask     = (const int*)d_in[10];
    const float* W_dyn   = (const float*)d_in[11];
    const float* W_pmcat = (const float*)d_in[12];
    const float* W_time  = (const float*)d_in[13];
    const float* W_llctx = (const float*)d_in[14];
    const float* W_pmctx = (const float*)d_in[15];
    const float* W_rbctx = (const float*)d_in[16];
    const float* W_cc1   = (const float*)d_in[17];
    const float* b_cc1   = (const float*)d_in[18];
    const float* W_cc2   = (const float*)d_in[19];
    const float* b_cc2   = (const float*)d_in[20];
    const float* Wq      = (const float*)d_in[21];
    const float* Wk      = (const float*)d_in[22];
    const float* Wv      = (const float*)d_in[23];
    const float* Wshk    = (const float*)d_in[24];
    const float* W_mhc   = (const float*)d_in[25];
    const float* b_mhc   = (const float*)d_in[26];
    (void)in_sizes; (void)n_in; (void)out_size; (void)ws_size;

    float* w = (float*)d_ws;
    size_t off = 0;
    auto alloc = [&](size_t n) { float* p = w + off; off += n; return p; };

    float* dallA  = alloc((size_t)B_ * A_);
    float* remain = alloc((size_t)B_ * P_);
    int*   idxw   = (int*)alloc((size_t)B_ * P_);
    int*   idxs   = (int*)alloc((size_t)B_ * P_);
    float* cvec   = alloc(2048);
    float* Gll    = alloc((size_t)B_ * 1024);
    float* colemb = alloc((size_t)B_ * NS_ * D_);
    float* E      = alloc((size_t)B_ * A_ * D_);
    float* KVS    = alloc((size_t)B_ * A_ * 1536);    // 107 MB
    float* Xpm    = alloc((size_t)B_ * D_);
    float* Xrb    = alloc((size_t)B_ * D_);
    float* ctx    = alloc((size_t)B_ * 3 * D_);
    float* hid    = alloc((size_t)B_ * D_);
    float* ctxout = alloc((size_t)B_ * D_);
    float* Qb     = alloc((size_t)B_ * D_);
    float* OUTb   = alloc((size_t)B_ * D_);
    float* MHb    = alloc((size_t)B_ * D_);
    unsigned short* Cpack = (unsigned short*)alloc((size_t)B_ * NS_ * 1024 / 2);
    unsigned short* Gpack = (unsigned short*)alloc((size_t)B_ * A_ * 1024 / 2);
    unsigned short* Epack = (unsigned short*)alloc((size_t)B_ * A_ * 1024 / 2);
    unsigned short* Wpack = (unsigned short*)alloc((size_t)(2 * 524288 + 2 * 1572864) / 2);

    const unsigned short* Wp1   = Wpack;
    const unsigned short* Wp2   = Wpack + 524288;
    const unsigned short* Wkvs1 = Wpack + 1048576;
    const unsigned short* Wkvs2 = Wpack + 1048576 + 1572864;

    prep_kernel<<<B_, 64, 0, stream>>>(clockp, lpet, loc_id, robot_loc, lhw,
                                       lstage, dallA, remain, idxw, idxs);
    cvec_kernel<<<8, 256, 0, stream>>>(W_dyn, W_time, W_pmcat, Wk, Wv, Wshk, cvec);
    packW_kernel<<<dim3(512, 8), 128, 0, stream>>>(W_pmcat, Wk, Wv, Wshk, Wpack);
    packcol_kernel<<<B_ * NS_, 128, 0, stream>>>(enc_col, Cpack);
    gatherG_kernel<<<B_ * A_, 128, 0, stream>>>(enc_row, ll1, ll2, idxw, Gpack, Gll);

    // colemb = enc_col @ Wp1^T
    {
        GemmCfg c{};
        c.p[0] = {Cpack, Wp1, 0, 0};
        c.p[1] = {Cpack, Wp1, 0, 512};
        c.p[2] = {Cpack, Wp1, 512, 0};
        c.npass = 3; c.C = colemb; c.ldc = 512;
        gemm_mfma<<<dim3(4, (B_ * NS_) / 128), 256, 0, stream>>>(c);
    }
    // E = G @ Wp2^T with fused assemble epilogue (colemb gather + rank1 + split)
    {
        GemmCfg c{};
        c.p[0] = {Gpack, Wp2, 0, 0};
        c.p[1] = {Gpack, Wp2, 0, 512};
        c.p[2] = {Gpack, Wp2, 512, 0};
        c.npass = 3; c.C = E; c.ldc = 512;
        c.fuseE = 1; c.colemb = colemb; c.c_pm = cvec; c.remain = remain;
        c.idxs = idxs; c.Epack = Epack;
        gemm_mfma<<<dim3(4, (B_ * A_) / 128), 256, 0, stream>>>(c);
    }
    // KVS[:,0:512]=K, [512:1024]=V, [1024:1536]=SHK — one merged GEMM
    {
        GemmCfg c{};
        c.p[0] = {Gpack, Wkvs2, 0, 0};  c.p[1] = {Gpack, Wkvs2, 0, 512};
        c.p[2] = {Gpack, Wkvs2, 512, 0};
        c.p[3] = {Epack, Wkvs1, 0, 0};  c.p[4] = {Epack, Wkvs1, 0, 512};
        c.p[5] = {Epack, Wkvs1, 512, 0};
        c.npass = 6; c.C = KVS; c.ldc = 1536;
        c.r1row = dallA; c.r1col = cvec + 512;
        gemm_mfma<<<dim3(12, (B_ * A_) / 128), 256, 0, stream>>>(c);
    }

    meanrb_kernel<<<B_, 128, 0, stream>>>(E, robot_loc, Xpm, Xrb);

    // ctx = [ll_ctx | pm_ctx | rb_ctx] in one z-indexed kernel
    {
        Ctx3Cfg c{Gll, Xpm, Xrb, W_llctx, W_pmctx, W_rbctx, ctx};
        ctx3_kernel<<<dim3(8, 8, 3), 256, 0, stream>>>(c);
    }
    gemm_nt<<<dim3(8, 8), 256, 0, stream>>>(ctx, 3 * D_, W_cc1, 3 * D_, hid, D_,
                                            3 * D_, b_cc1, 1);
    gemm_nt<<<dim3(8, 8), 256, 0, stream>>>(hid, D_, W_cc2, D_, ctxout, D_,
                                            D_, b_cc2, 0);
    gemm_nt<<<dim3(8, 8), 256, 0, stream>>>(ctxout, D_, Wq, D_, Qb, D_,
                                            D_, nullptr, 0);

    attn_kernel<<<dim3(H_, B_), 64, 0, stream>>>(Qb, KVS, amask, OUTb);

    gemm_nt<<<dim3(8, 8), 256, 0, stream>>>(OUTb, D_, W_mhc, D_, MHb, D_,
                                            D_, b_mhc, 0);

    final_kernel<<<B_, 320, 0, stream>>>(MHb, KVS, amask, (float*)d_out);
}

// Round 5
// 1050.304 us; speedup vs baseline: 1.0150x; 1.0150x over previous
//
#include <hip/hip_runtime.h>
#include <hip/hip_bf16.h>

// CONCATNet forward. B=512 NW=256 NS=8 P=32 D=512 H=16 QK=32 A=34
// R5: XOR-swizzled LDS layout in gemm_mfma. Rows are 64B (16 banks), so the
// naive layout gives 8-way bank conflicts on ds_read_b128 fragment reads
// (2.0e7 SQ_LDS_BANK_CONFLICT, MfmaUtil 23%). Chunk q of row R is stored at
// position q ^ (((R&15)>>1)&3); staging lanes permute their global chunk
// (coalescing preserved), fragment reads apply the same XOR -> 2-way (free).
// action_mask arrives as int32 (harness widens bool).

#define B_  512
#define NW_ 256
#define NS_ 8
#define P_  32
#define D_  512
#define H_  16
#define QK_ 32
#define A_  34

typedef __attribute__((ext_vector_type(8))) short short8;
typedef __attribute__((ext_vector_type(4))) float floatx4;

// ---------------------------------------------------------------- bf16 split
__device__ __forceinline__ unsigned short bf16_rne(float x) {
    union { float f; unsigned int u; } c; c.f = x;
    unsigned int u = c.u;
    return (unsigned short)((u + 0x7fffu + ((u >> 16) & 1u)) >> 16);
}
__device__ __forceinline__ float bf16_f(unsigned short h) {
    union { unsigned int u; float f; } c; c.u = ((unsigned int)h) << 16;
    return c.f;
}
__device__ __forceinline__ void bf16_split(float x, unsigned short& hi, unsigned short& lo) {
    hi = bf16_rne(x);
    lo = bf16_rne(x - bf16_f(hi));
}

__device__ __forceinline__ void gload16(const void* g, void* l) {
    __builtin_amdgcn_global_load_lds(
        (const __attribute__((address_space(1))) void*)g,
        (__attribute__((address_space(3))) void*)l, 16, 0, 0);
}

// ---------------------------------------------------------------- MFMA GEMM
struct Pass { const unsigned short* a; const unsigned short* w; int aoff; int woff; };
struct GemmCfg {
    Pass p[6];
    int npass;
    float* C;
    int ldc;
    const float* r1row;
    const float* r1col;
    int fuseE;
    const float* colemb;
    const float* c_pm;
    const float* remain;
    const int* idxs;
    unsigned short* Epack;
};

__global__ __launch_bounds__(256) void gemm_mfma(GemmCfg cfg)
{
    __shared__ __align__(16) unsigned short As[128 * 32];
    __shared__ __align__(16) unsigned short Ws[128 * 32];

    const int tid  = threadIdx.x;
    const int m0   = blockIdx.y * 128;
    const int n0   = blockIdx.x * 128;
    const int wave = tid >> 6;
    const int lane = tid & 63;
    const int wr   = wave >> 1;
    const int wc   = wave & 1;
    const int lrow = tid >> 2;
    // swizzled staging chunk: lane's global k-chunk = (tid&3) ^ ((tid>>3)&3)
    const int lpart = (((tid & 3) ^ ((tid >> 3) & 3)) << 3);

    floatx4 acc[4][4];
#pragma unroll
    for (int i = 0; i < 4; i++)
#pragma unroll
        for (int j = 0; j < 4; j++) acc[i][j] = (floatx4)0.f;

    const int q = lane >> 4;
    const int r = lane & 15;
    const int swz = (r >> 1) & 3;          // fragment-read XOR
    const int qs = (q ^ swz) << 3;         // swizzled chunk offset (shorts)

    for (int pi = 0; pi < cfg.npass; ++pi) {
        const unsigned short* Ab = cfg.p[pi].a + (size_t)m0 * 1024 + cfg.p[pi].aoff;
        const unsigned short* Wb = cfg.p[pi].w + (size_t)n0 * 1024 + cfg.p[pi].woff;
        for (int k0 = 0; k0 < 512; k0 += 32) {
            __syncthreads();
            gload16(Ab + (size_t)lrow * 1024 + k0 + lpart,        &As[tid * 8]);
            gload16(Ab + (size_t)(lrow + 64) * 1024 + k0 + lpart, &As[2048 + tid * 8]);
            gload16(Wb + (size_t)lrow * 1024 + k0 + lpart,        &Ws[tid * 8]);
            gload16(Wb + (size_t)(lrow + 64) * 1024 + k0 + lpart, &Ws[2048 + tid * 8]);
            __syncthreads();

            short8 af[4], wf[4];
#pragma unroll
            for (int i = 0; i < 4; i++)
                af[i] = *(const short8*)&As[(wr * 64 + i * 16 + r) * 32 + qs];
#pragma unroll
            for (int j = 0; j < 4; j++)
                wf[j] = *(const short8*)&Ws[(wc * 64 + j * 16 + r) * 32 + qs];
#pragma unroll
            for (int i = 0; i < 4; i++)
#pragma unroll
                for (int j = 0; j < 4; j++)
                    acc[i][j] = __builtin_amdgcn_mfma_f32_16x16x32_bf16(
                        af[i], wf[j], acc[i][j], 0, 0, 0);
        }
    }

    if (cfg.fuseE) {
#pragma unroll
        for (int j = 0; j < 4; j++) {
            const int col = n0 + wc * 64 + j * 16 + r;
            const float cpm = cfg.c_pm[col];
#pragma unroll
            for (int i = 0; i < 4; i++) {
                const int rowb = m0 + wr * 64 + i * 16 + q * 4;
#pragma unroll
                for (int reg = 0; reg < 4; reg++) {
                    const int m = rowb + reg;
                    const int b = m / A_;
                    const int a = m - b * A_;
                    float v = 0.f;
                    if (a >= 2) {
                        const int p = a - 2;
                        const int s = cfg.idxs[b * P_ + p];
                        v = acc[i][j][reg]
                          + cfg.colemb[((size_t)(b * NS_ + s)) * 512 + col]
                          + cfg.remain[b * P_ + p] * cpm;
                    }
                    cfg.C[(size_t)m * 512 + col] = v;
                    unsigned short hh, ll;
                    bf16_split(v, hh, ll);
                    cfg.Epack[(size_t)m * 1024 + col] = hh;
                    cfg.Epack[(size_t)m * 1024 + 512 + col] = ll;
                }
            }
        }
    } else {
#pragma unroll
        for (int j = 0; j < 4; j++) {
            const int col = n0 + wc * 64 + j * 16 + r;
            const float r1c = cfg.r1col ? cfg.r1col[col] : 0.f;
#pragma unroll
            for (int i = 0; i < 4; i++) {
                const int rowb = m0 + wr * 64 + i * 16 + q * 4;
#pragma unroll
                for (int reg = 0; reg < 4; reg++) {
                    float v = acc[i][j][reg];
                    if (cfg.r1row) v += cfg.r1row[rowb + reg] * r1c;
                    cfg.C[(size_t)(rowb + reg) * cfg.ldc + col] = v;
                }
            }
        }
    }
}

// ---------------------------------------------------------------- fp32 GEMM (small)
#define BM 64
#define BN 64
#define BK 32
__global__ __launch_bounds__(256) void gemm_nt(
    const float* __restrict__ A, int lda,
    const float* __restrict__ W, int ldw,
    float* __restrict__ C, int ldc,
    int K,
    const float* __restrict__ bias,
    int relu)
{
    __shared__ float As[BK][BM + 4];
    __shared__ float Wsm[BK][BN + 4];

    const int tid = threadIdx.x;
    const int m0 = blockIdx.y * BM;
    const int n0 = blockIdx.x * BN;
    const int ty = tid >> 4;
    const int tx = tid & 15;
    const int lrow = tid >> 2;
    const int lcol = (tid & 3) << 3;

    float acc[4][4];
#pragma unroll
    for (int i = 0; i < 4; i++)
#pragma unroll
        for (int j = 0; j < 4; j++) acc[i][j] = 0.f;

    const float* Ablk = A + (size_t)m0 * lda;
    const float* Wblk = W + (size_t)n0 * ldw;

    for (int k0 = 0; k0 < K; k0 += BK) {
        const float* ap = Ablk + (size_t)lrow * lda + k0 + lcol;
        float4 a0 = *(const float4*)(ap);
        float4 a1 = *(const float4*)(ap + 4);
        const float* wp = Wblk + (size_t)lrow * ldw + k0 + lcol;
        float4 w0 = *(const float4*)(wp);
        float4 w1 = *(const float4*)(wp + 4);

        __syncthreads();
        As[lcol + 0][lrow] = a0.x; As[lcol + 1][lrow] = a0.y;
        As[lcol + 2][lrow] = a0.z; As[lcol + 3][lrow] = a0.w;
        As[lcol + 4][lrow] = a1.x; As[lcol + 5][lrow] = a1.y;
        As[lcol + 6][lrow] = a1.z; As[lcol + 7][lrow] = a1.w;
        Wsm[lcol + 0][lrow] = w0.x; Wsm[lcol + 1][lrow] = w0.y;
        Wsm[lcol + 2][lrow] = w0.z; Wsm[lcol + 3][lrow] = w0.w;
        Wsm[lcol + 4][lrow] = w1.x; Wsm[lcol + 5][lrow] = w1.y;
        Wsm[lcol + 6][lrow] = w1.z; Wsm[lcol + 7][lrow] = w1.w;
        __syncthreads();

#pragma unroll
        for (int k = 0; k < BK; k++) {
            const float4 av = *(const float4*)(&As[k][ty << 2]);
            const float4 wv = *(const float4*)(&Wsm[k][tx << 2]);
            acc[0][0] += av.x * wv.x; acc[0][1] += av.x * wv.y;
            acc[0][2] += av.x * wv.z; acc[0][3] += av.x * wv.w;
            acc[1][0] += av.y * wv.x; acc[1][1] += av.y * wv.y;
            acc[1][2] += av.y * wv.z; acc[1][3] += av.y * wv.w;
            acc[2][0] += av.z * wv.x; acc[2][1] += av.z * wv.y;
            acc[2][2] += av.z * wv.z; acc[2][3] += av.z * wv.w;
            acc[3][0] += av.w * wv.x; acc[3][1] += av.w * wv.y;
            acc[3][2] += av.w * wv.z; acc[3][3] += av.w * wv.w;
        }
    }

    const int mbase = m0 + (ty << 2);
    const int nbase = n0 + (tx << 2);
    float4 bv = make_float4(0.f, 0.f, 0.f, 0.f);
    if (bias) bv = *(const float4*)(bias + nbase);

#pragma unroll
    for (int i = 0; i < 4; i++) {
        float* cp = C + (size_t)(mbase + i) * ldc + nbase;
        float4 v = make_float4(acc[i][0], acc[i][1], acc[i][2], acc[i][3]);
        if (bias) { v.x += bv.x; v.y += bv.y; v.z += bv.z; v.w += bv.w; }
        if (relu) {
            v.x = fmaxf(v.x, 0.f); v.y = fmaxf(v.y, 0.f);
            v.z = fmaxf(v.z, 0.f); v.w = fmaxf(v.w, 0.f);
        }
        *(float4*)cp = v;
    }
}

// ---------------------------------------------------------------- ctx 3-in-1
struct Ctx3Cfg {
    const float* A0; const float* A1; const float* A2;
    const float* W0; const float* W1; const float* W2;
    float* C;
};
__global__ __launch_bounds__(256) void ctx3_kernel(Ctx3Cfg cfg)
{
    const int z = blockIdx.z;
    const float* A = (z == 0) ? cfg.A0 : (z == 1) ? cfg.A1 : cfg.A2;
    const float* W = (z == 0) ? cfg.W0 : (z == 1) ? cfg.W1 : cfg.W2;
    const int K = (z == 0) ? 1024 : 512;
    const int lda = K, ldw = K;
    float* C = cfg.C + z * 512;
    const int ldc = 1536;

    __shared__ float As[BK][BM + 4];
    __shared__ float Wsm[BK][BN + 4];

    const int tid = threadIdx.x;
    const int m0 = blockIdx.y * BM;
    const int n0 = blockIdx.x * BN;
    const int ty = tid >> 4;
    const int tx = tid & 15;
    const int lrow = tid >> 2;
    const int lcol = (tid & 3) << 3;

    float acc[4][4];
#pragma unroll
    for (int i = 0; i < 4; i++)
#pragma unroll
        for (int j = 0; j < 4; j++) acc[i][j] = 0.f;

    const float* Ablk = A + (size_t)m0 * lda;
    const float* Wblk = W + (size_t)n0 * ldw;

    for (int k0 = 0; k0 < K; k0 += BK) {
        const float* ap = Ablk + (size_t)lrow * lda + k0 + lcol;
        float4 a0 = *(const float4*)(ap);
        float4 a1 = *(const float4*)(ap + 4);
        const float* wp = Wblk + (size_t)lrow * ldw + k0 + lcol;
        float4 w0 = *(const float4*)(wp);
        float4 w1 = *(const float4*)(wp + 4);

        __syncthreads();
        As[lcol + 0][lrow] = a0.x; As[lcol + 1][lrow] = a0.y;
        As[lcol + 2][lrow] = a0.z; As[lcol + 3][lrow] = a0.w;
        As[lcol + 4][lrow] = a1.x; As[lcol + 5][lrow] = a1.y;
        As[lcol + 6][lrow] = a1.z; As[lcol + 7][lrow] = a1.w;
        Wsm[lcol + 0][lrow] = w0.x; Wsm[lcol + 1][lrow] = w0.y;
        Wsm[lcol + 2][lrow] = w0.z; Wsm[lcol + 3][lrow] = w0.w;
        Wsm[lcol + 4][lrow] = w1.x; Wsm[lcol + 5][lrow] = w1.y;
        Wsm[lcol + 6][lrow] = w1.z; Wsm[lcol + 7][lrow] = w1.w;
        __syncthreads();

#pragma unroll
        for (int k = 0; k < BK; k++) {
            const float4 av = *(const float4*)(&As[k][ty << 2]);
            const float4 wv = *(const float4*)(&Wsm[k][tx << 2]);
            acc[0][0] += av.x * wv.x; acc[0][1] += av.x * wv.y;
            acc[0][2] += av.x * wv.z; acc[0][3] += av.x * wv.w;
            acc[1][0] += av.y * wv.x; acc[1][1] += av.y * wv.y;
            acc[1][2] += av.y * wv.z; acc[1][3] += av.y * wv.w;
            acc[2][0] += av.z * wv.x; acc[2][1] += av.z * wv.y;
            acc[2][2] += av.z * wv.z; acc[2][3] += av.z * wv.w;
            acc[3][0] += av.w * wv.x; acc[3][1] += av.w * wv.y;
            acc[3][2] += av.w * wv.z; acc[3][3] += av.w * wv.w;
        }
    }

    const int mbase = m0 + (ty << 2);
    const int nbase = n0 + (tx << 2);
#pragma unroll
    for (int i = 0; i < 4; i++) {
        float* cp = C + (size_t)(mbase + i) * ldc + nbase;
        *(float4*)cp = make_float4(acc[i][0], acc[i][1], acc[i][2], acc[i][3]);
    }
}

// ---------------------------------------------------------------- prep scalars
__global__ __launch_bounds__(64) void prep_kernel(
    const float* __restrict__ clockp, const float* __restrict__ lpet,
    const int* __restrict__ loc_id, const int* __restrict__ robot_loc,
    const int* __restrict__ lhw, const int* __restrict__ lstage,
    float* __restrict__ dallA, float* __restrict__ remain,
    int* __restrict__ idxw, int* __restrict__ idxs)
{
    const int b = blockIdx.x;
    const int t = threadIdx.x;
    const float ck = clockp[b];
    const int rb = robot_loc[b];
    if (t < P_) {
        const float endt = lpet[b * P_ + t];
        const int lid = loc_id[b * P_ + t];
        const float pk = ck + 3.f * (lid != rb ? 1.f : 0.f);
        dallA[b * A_ + 2 + t] = (fmaxf(endt, pk) + 9.f - ck) * (1.f / 300.f);
        remain[b * P_ + t] = fmaxf(endt - ck, 0.f) * (1.f / 300.f);
        const int w = lhw[b * P_ + t];
        idxw[b * P_ + t] = (w >= 0) ? w : NW_;
        idxs[b * P_ + t] = lstage[b * P_ + t] - 1;
    } else if (t == P_) {
        const float d0 = (3.f * (rb != 0 ? 1.f : 0.f) + 9.f) * (1.f / 300.f);
        dallA[b * A_ + 0] = d0;
        dallA[b * A_ + 1] = d0;
    }
}

// ---------------------------------------------------------------- rank-1 vecs
__global__ __launch_bounds__(256) void cvec_kernel(
    const float* __restrict__ W_dyn, const float* __restrict__ W_time,
    const float* __restrict__ W_pmcat, const float* __restrict__ Wk,
    const float* __restrict__ Wv, const float* __restrict__ Wshk,
    float* __restrict__ cvec)
{
    const int id = blockIdx.x * 256 + threadIdx.x;
    const int vec = id >> 9;
    const int h = id & 511;
    float s = 0.f;
    if (vec == 0) {
        const float* wp = W_pmcat + (size_t)h * 1536 + 1024;
        for (int j = 0; j < 512; j++) s += W_dyn[j * 2] * wp[j];
    } else {
        const float* Wm = (vec == 1) ? Wk : (vec == 2) ? Wv : Wshk;
        const float* wp = Wm + (size_t)h * 1536 + 1024;
        for (int j = 0; j < 512; j++) s += W_time[j] * wp[j];
    }
    cvec[id] = s;
}

// ---------------------------------------------------------------- pack weights
__global__ __launch_bounds__(128) void packW_kernel(
    const float* __restrict__ Wp, const float* __restrict__ Wk,
    const float* __restrict__ Wv, const float* __restrict__ Wsh,
    unsigned short* __restrict__ out)
{
    const int row = blockIdx.x;
    const int ms = blockIdx.y;
    const int mat = ms >> 1, seg = ms & 1;
    const int d = threadIdx.x * 4;
    const float* src = (mat == 0 ? Wp : mat == 1 ? Wk : mat == 2 ? Wv : Wsh)
                       + (size_t)row * 1536 + seg * 512 + d;
    const float4 v = *(const float4*)src;
    unsigned short h0, h1, h2, h3, l0, l1, l2, l3;
    bf16_split(v.x, h0, l0); bf16_split(v.y, h1, l1);
    bf16_split(v.z, h2, l2); bf16_split(v.w, h3, l3);
    unsigned short* dst;
    if (mat == 0) {
        dst = out + (size_t)seg * 524288 + (size_t)row * 1024 + d;
    } else {
        const int rr = (mat - 1) * 512 + row;
        dst = out + 1048576 + (size_t)seg * 1572864 + (size_t)rr * 1024 + d;
    }
    *(ushort4*)dst = make_ushort4(h0, h1, h2, h3);
    *(ushort4*)(dst + 512) = make_ushort4(l0, l1, l2, l3);
}

// ---------------------------------------------------------------- convert enc_col
__global__ __launch_bounds__(128) void packcol_kernel(
    const float* __restrict__ src, unsigned short* __restrict__ dst)
{
    const int row = blockIdx.x;
    const int d = threadIdx.x * 4;
    const float4 v = *(const float4*)(src + (size_t)row * 512 + d);
    unsigned short h0, h1, h2, h3, l0, l1, l2, l3;
    bf16_split(v.x, h0, l0); bf16_split(v.y, h1, l1);
    bf16_split(v.z, h2, l2); bf16_split(v.w, h3, l3);
    unsigned short* dp = dst + (size_t)row * 1024 + d;
    *(ushort4*)dp = make_ushort4(h0, h1, h2, h3);
    *(ushort4*)(dp + 512) = make_ushort4(l0, l1, l2, l3);
}

// ---------------------------------------------------------------- gather G
__global__ __launch_bounds__(128) void gatherG_kernel(
    const float* __restrict__ enc_row, const int* __restrict__ ll1,
    const int* __restrict__ ll2, const int* __restrict__ idxw,
    unsigned short* __restrict__ Gpack, float* __restrict__ Gll)
{
    const int ba = blockIdx.x;
    const int b = ba / A_, a = ba % A_;
    const int d = threadIdx.x * 4;
    int row;
    if (a == 0) row = ll1[b];
    else if (a == 1) row = ll2[b];
    else row = idxw[b * P_ + a - 2];
    float4 v = make_float4(0.f, 0.f, 0.f, 0.f);
    if (row < NW_) v = *(const float4*)(enc_row + ((size_t)b * NW_ + row) * D_ + d);
    unsigned short h0, h1, h2, h3, l0, l1, l2, l3;
    bf16_split(v.x, h0, l0); bf16_split(v.y, h1, l1);
    bf16_split(v.z, h2, l2); bf16_split(v.w, h3, l3);
    unsigned short* dp = Gpack + (size_t)ba * 1024 + d;
    *(ushort4*)dp = make_ushort4(h0, h1, h2, h3);
    *(ushort4*)(dp + 512) = make_ushort4(l0, l1, l2, l3);
    if (a < 2) *(float4*)(Gll + (size_t)b * 1024 + a * 512 + d) = v;
}

// ---------------------------------------------------------------- mean + rb gather
__global__ __launch_bounds__(128) void meanrb_kernel(
    const float* __restrict__ E, const int* __restrict__ robot_loc,
    float* __restrict__ Xpm, float* __restrict__ Xrb)
{
    const int b = blockIdx.x;
    const int d = threadIdx.x * 4;
    const float* ep = E + ((size_t)b * A_ + 2) * D_ + d;
    float4 acc = make_float4(0.f, 0.f, 0.f, 0.f);
    for (int p = 0; p < P_; p++) {
        const float4 v = *(const float4*)(ep + (size_t)p * D_);
        acc.x += v.x; acc.y += v.y; acc.z += v.z; acc.w += v.w;
    }
    const float inv = 1.f / (float)P_;
    acc.x *= inv; acc.y *= inv; acc.z *= inv; acc.w *= inv;
    *(float4*)(Xpm + (size_t)b * D_ + d) = acc;
    const int rb = robot_loc[b];
    *(float4*)(Xrb + (size_t)b * D_ + d) =
        *(const float4*)(E + ((size_t)b * A_ + 2 + rb) * D_ + d);
}

// ---------------------------------------------------------------- attention
__global__ __launch_bounds__(64) void attn_kernel(
    const float* __restrict__ Q, const float* __restrict__ KVS,
    const int* __restrict__ mask, float* __restrict__ OUT)
{
    const int h = blockIdx.x, b = blockIdx.y;
    const int lane = threadIdx.x;
    __shared__ float w[A_];
    float s;
    if (lane < A_) {
        const float* qp = Q + (size_t)b * D_ + h * QK_;
        const float* kp = KVS + ((size_t)b * A_ + lane) * 1536 + h * QK_;
        float acc = 0.f;
#pragma unroll
        for (int i = 0; i < QK_; i += 4) {
            const float4 qv = *(const float4*)(qp + i);
            const float4 kv = *(const float4*)(kp + i);
            acc += qv.x * kv.x + qv.y * kv.y + qv.z * kv.z + qv.w * kv.w;
        }
        s = acc * 0.17677669529663687f;
        if (!mask[b * A_ + lane]) s += -1e10f;
    } else {
        s = -1e30f;
    }
    float m = s;
    for (int o = 32; o; o >>= 1) m = fmaxf(m, __shfl_xor(m, o));
    float p = (lane < A_) ? expf(s - m) : 0.f;
    float sum = p;
    for (int o = 32; o; o >>= 1) sum += __shfl_xor(sum, o);
    if (lane < A_) w[lane] = p / sum;
    __syncthreads();
    if (lane < QK_) {
        const float* vp = KVS + (size_t)b * A_ * 1536 + 512 + h * QK_ + lane;
        float acc = 0.f;
#pragma unroll 2
        for (int a = 0; a < A_; a++) acc += w[a] * vp[(size_t)a * 1536];
        OUT[(size_t)b * D_ + h * QK_ + lane] = acc;
    }
}

// ---------------------------------------------------------------- final
__global__ __launch_bounds__(320) void final_kernel(
    const float* __restrict__ MH, const float* __restrict__ KVS,
    const int* __restrict__ mask, float* __restrict__ out)
{
    const int b = blockIdx.x;
    const int t = threadIdx.x;
    __shared__ float mh[D_];
    __shared__ float sc[A_];
    for (int i = t; i < D_; i += 320) mh[i] = MH[(size_t)b * D_ + i];
    __syncthreads();
    const int a = t >> 3;
    const int part = t & 7;
    float s = 0.f;
    if (a < A_) {
        const float* sp = KVS + ((size_t)b * A_ + a) * 1536 + 1024 + part * 64;
        const float* mp = mh + part * 64;
#pragma unroll
        for (int i = 0; i < 64; i += 4) {
            const float4 v = *(const float4*)(sp + i);
            s += mp[i] * v.x + mp[i + 1] * v.y + mp[i + 2] * v.z + mp[i + 3] * v.w;
        }
    }
    s += __shfl_down(s, 4, 8);
    s += __shfl_down(s, 2, 8);
    s += __shfl_down(s, 1, 8);
    if (a < A_ && part == 0) {
        float v = 10.f * tanhf(s * 0.044194173824159216f);
        if (!mask[b * A_ + a]) v += -1e10f;
        sc[a] = v;
    }
    __syncthreads();
    if (t < 64) {
        float x = (t < A_) ? sc[t] : -1e30f;
        float m = x;
        for (int o = 32; o; o >>= 1) m = fmaxf(m, __shfl_xor(m, o));
        float p = (t < A_) ? expf(x - m) : 0.f;
        float sum = p;
        for (int o = 32; o; o >>= 1) sum += __shfl_xor(sum, o);
        if (t < A_) out[(size_t)b * A_ + t] = p / sum;
    }
}

// ---------------------------------------------------------------- launcher
extern "C" void kernel_launch(void* const* d_in, const int* in_sizes, int n_in,
                              void* d_out, int out_size, void* d_ws, size_t ws_size,
                              hipStream_t stream)
{
    const float* enc_row = (const float*)d_in[0];
    const float* enc_col = (const float*)d_in[1];
    const float* clockp  = (const float*)d_in[2];
    const float* lpet    = (const float*)d_in[3];
    const int* loc_id    = (const int*)d_in[4];
    const int* robot_loc = (const int*)d_in[5];
    const int* lhw       = (const int*)d_in[6];
    const int* lstage    = (const int*)d_in[7];
    const int* ll1       = (const int*)d_in[8];
    const int* ll2       = (const int*)d_in[9];
    const int* amask     = (const int*)d_in[10];
    const float* W_dyn   = (const float*)d_in[11];
    const float* W_pmcat = (const float*)d_in[12];
    const float* W_time  = (const float*)d_in[13];
    const float* W_llctx = (const float*)d_in[14];
    const float* W_pmctx = (const float*)d_in[15];
    const float* W_rbctx = (const float*)d_in[16];
    const float* W_cc1   = (const float*)d_in[17];
    const float* b_cc1   = (const float*)d_in[18];
    const float* W_cc2   = (const float*)d_in[19];
    const float* b_cc2   = (const float*)d_in[20];
    const float* Wq      = (const float*)d_in[21];
    const float* Wk      = (const float*)d_in[22];
    const float* Wv      = (const float*)d_in[23];
    const float* Wshk    = (const float*)d_in[24];
    const float* W_mhc   = (const float*)d_in[25];
    const float* b_mhc   = (const float*)d_in[26];
    (void)in_sizes; (void)n_in; (void)out_size; (void)ws_size;

    float* w = (float*)d_ws;
    size_t off = 0;
    auto alloc = [&](size_t n) { float* p = w + off; off += n; return p; };

    float* dallA  = alloc((size_t)B_ * A_);
    float* remain = alloc((size_t)B_ * P_);
    int*   idxw   = (int*)alloc((size_t)B_ * P_);
    int*   idxs   = (int*)alloc((size_t)B_ * P_);
    float* cvec   = alloc(2048);
    float* Gll    = alloc((size_t)B_ * 1024);
    float* colemb = alloc((size_t)B_ * NS_ * D_);
    float* E      = alloc((size_t)B_ * A_ * D_);
    float* KVS    = alloc((size_t)B_ * A_ * 1536);
    float* Xpm    = alloc((size_t)B_ * D_);
    float* Xrb    = alloc((size_t)B_ * D_);
    float* ctx    = alloc((size_t)B_ * 3 * D_);
    float* hid    = alloc((size_t)B_ * D_);
    float* ctxout = alloc((size_t)B_ * D_);
    float* Qb     = alloc((size_t)B_ * D_);
    float* OUTb   = alloc((size_t)B_ * D_);
    float* MHb    = alloc((size_t)B_ * D_);
    unsigned short* Cpack = (unsigned short*)alloc((size_t)B_ * NS_ * 1024 / 2);
    unsigned short* Gpack = (unsigned short*)alloc((size_t)B_ * A_ * 1024 / 2);
    unsigned short* Epack = (unsigned short*)alloc((size_t)B_ * A_ * 1024 / 2);
    unsigned short* Wpack = (unsigned short*)alloc((size_t)(2 * 524288 + 2 * 1572864) / 2);

    const unsigned short* Wp1   = Wpack;
    const unsigned short* Wp2   = Wpack + 524288;
    const unsigned short* Wkvs1 = Wpack + 1048576;
    const unsigned short* Wkvs2 = Wpack + 1048576 + 1572864;

    prep_kernel<<<B_, 64, 0, stream>>>(clockp, lpet, loc_id, robot_loc, lhw,
                                       lstage, dallA, remain, idxw, idxs);
    cvec_kernel<<<8, 256, 0, stream>>>(W_dyn, W_time, W_pmcat, Wk, Wv, Wshk, cvec);
    packW_kernel<<<dim3(512, 8), 128, 0, stream>>>(W_pmcat, Wk, Wv, Wshk, Wpack);
    packcol_kernel<<<B_ * NS_, 128, 0, stream>>>(enc_col, Cpack);
    gatherG_kernel<<<B_ * A_, 128, 0, stream>>>(enc_row, ll1, ll2, idxw, Gpack, Gll);

    // colemb = enc_col @ Wp1^T
    {
        GemmCfg c{};
        c.p[0] = {Cpack, Wp1, 0, 0};
        c.p[1] = {Cpack, Wp1, 0, 512};
        c.p[2] = {Cpack, Wp1, 512, 0};
        c.npass = 3; c.C = colemb; c.ldc = 512;
        gemm_mfma<<<dim3(4, (B_ * NS_) / 128), 256, 0, stream>>>(c);
    }
    // E = G @ Wp2^T with fused assemble epilogue
    {
        GemmCfg c{};
        c.p[0] = {Gpack, Wp2, 0, 0};
        c.p[1] = {Gpack, Wp2, 0, 512};
        c.p[2] = {Gpack, Wp2, 512, 0};
        c.npass = 3; c.C = E; c.ldc = 512;
        c.fuseE = 1; c.colemb = colemb; c.c_pm = cvec; c.remain = remain;
        c.idxs = idxs; c.Epack = Epack;
        gemm_mfma<<<dim3(4, (B_ * A_) / 128), 256, 0, stream>>>(c);
    }
    // KVS merged GEMM
    {
        GemmCfg c{};
        c.p[0] = {Gpack, Wkvs2, 0, 0};  c.p[1] = {Gpack, Wkvs2, 0, 512};
        c.p[2] = {Gpack, Wkvs2, 512, 0};
        c.p[3] = {Epack, Wkvs1, 0, 0};  c.p[4] = {Epack, Wkvs1, 0, 512};
        c.p[5] = {Epack, Wkvs1, 512, 0};
        c.npass = 6; c.C = KVS; c.ldc = 1536;
        c.r1row = dallA; c.r1col = cvec + 512;
        gemm_mfma<<<dim3(12, (B_ * A_) / 128), 256, 0, stream>>>(c);
    }

    meanrb_kernel<<<B_, 128, 0, stream>>>(E, robot_loc, Xpm, Xrb);

    {
        Ctx3Cfg c{Gll, Xpm, Xrb, W_llctx, W_pmctx, W_rbctx, ctx};
        ctx3_kernel<<<dim3(8, 8, 3), 256, 0, stream>>>(c);
    }
    gemm_nt<<<dim3(8, 8), 256, 0, stream>>>(ctx, 3 * D_, W_cc1, 3 * D_, hid, D_,
                                            3 * D_, b_cc1, 1);
    gemm_nt<<<dim3(8, 8), 256, 0, stream>>>(hid, D_, W_cc2, D_, ctxout, D_,
                                            D_, b_cc2, 0);
    gemm_nt<<<dim3(8, 8), 256, 0, stream>>>(ctxout, D_, Wq, D_, Qb, D_,
                                            D_, nullptr, 0);

    attn_kernel<<<dim3(H_, B_), 64, 0, stream>>>(Qb, KVS, amask, OUTb);

    gemm_nt<<<dim3(8, 8), 256, 0, stream>>>(OUTb, D_, W_mhc, D_, MHb, D_,
                                            D_, b_mhc, 0);

    final_kernel<<<B_, 320, 0, stream>>>(MHb, KVS, amask, (float*)d_out);
}